// Round 1
// baseline (226.676 us; speedup 1.0000x reference)
//
#include <hip/hip_runtime.h>

// ViewLearner edge-scorer, factored:
//   P = node_emb @ W1[0:128,:]   (per node, 64 outputs)
//   Q = node_emb @ W1[128:256,:] (per node, 64 outputs)
//   logit[e] = relu(P[src]+Q[dst]+b1) . W2 + b2
// PQ stored as [N][128] fp32 in d_ws (25.6 MB): row = [P(64) | Q(64)].

#define HIDDEN 128
#define MLPD 64

// ---------------- Kernel 1: PQ precompute ([N,128] @ [128,128]) -------------
// Bc[k][j]: j<64 -> W1[k][j] (top half), j>=64 -> W1[k+128][j-64] (bottom half)
__global__ __launch_bounds__(256) void precompute_pq(
    const float* __restrict__ node_emb,   // [N,128]
    const float* __restrict__ W1,         // [256,64] row-major
    float* __restrict__ PQ,               // [N,128]
    int n_nodes)
{
    __shared__ float Bc[128 * 128];       // 64 KB... wait: 128*128*4 = 64KB; plus As below
    // NOTE: 128*128 floats = 64 KB would overflow with As; use bfloat-free split:
    // we actually allocate 128*128 = 16384 floats? That IS 64 KB. So shrink:
    // Bc stays full fp32 but As shares budget -> total must be <= 64 KB.
    // 128*96? No -- see static_assert below; we use 32-row A tile and full B:
    // 64 KB + 17 KB > 64 KB limit, so B is stored as two 32 KB halves? Simpler:
    // keep B full but in LDS we only fit if As is small. Solution: As in LDS
    // (32*132 floats = 16.9 KB) and Bc as 128x96?  -- NO. Final layout below.
    __shared__ float As[32 * 132];        // 16.9 KB, padded stride 132

    const int t = threadIdx.x;
    const int m0 = blockIdx.x * 32;

    // Load B into LDS: 16384 floats / 256 threads = 64 each (coalesced)
    for (int u = t; u < 128 * 128; u += 256) {
        int k = u >> 7, j = u & 127;
        Bc[u] = (j < 64) ? W1[k * 64 + j] : W1[(k + 128) * 64 + (j - 64)];
    }
    // Stage 32 A rows: 4096 floats (coalesced), padded LDS stride 132
    for (int u = t; u < 32 * 128; u += 256) {
        int r = u >> 7, k = u & 127;
        int m = m0 + r;
        As[r * 132 + k] = (m < n_nodes) ? node_emb[(size_t)m * 128 + k] : 0.f;
    }
    __syncthreads();

    // 256 threads = 32 col-groups x 8 row-groups; each thread: 4 rows x 4 cols
    const int tj = t & 31, tr = t >> 5;
    const int j0 = tj * 4, r0 = tr * 4;
    float4 acc[4];
    acc[0] = make_float4(0.f, 0.f, 0.f, 0.f);
    acc[1] = acc[0]; acc[2] = acc[0]; acc[3] = acc[0];

    for (int k = 0; k < 128; k += 4) {
        float4 b0 = *(const float4*)&Bc[(k + 0) * 128 + j0];
        float4 b1v = *(const float4*)&Bc[(k + 1) * 128 + j0];
        float4 b2v = *(const float4*)&Bc[(k + 2) * 128 + j0];
        float4 b3v = *(const float4*)&Bc[(k + 3) * 128 + j0];
        #pragma unroll
        for (int r = 0; r < 4; ++r) {
            float4 a = *(const float4*)&As[(r0 + r) * 132 + k];
            acc[r].x += a.x * b0.x + a.y * b1v.x + a.z * b2v.x + a.w * b3v.x;
            acc[r].y += a.x * b0.y + a.y * b1v.y + a.z * b2v.y + a.w * b3v.y;
            acc[r].z += a.x * b0.z + a.y * b1v.z + a.z * b2v.z + a.w * b3v.z;
            acc[r].w += a.x * b0.w + a.y * b1v.w + a.z * b2v.w + a.w * b3v.w;
        }
    }
    #pragma unroll
    for (int r = 0; r < 4; ++r) {
        int m = m0 + r0 + r;
        if (m < n_nodes)
            *(float4*)&PQ[(size_t)m * 128 + j0] = acc[r];
    }
}

// ---------------- Kernel 2: per-edge gather + tiny MLP ----------------------
// 16 lanes per edge; lane g handles channels 4g..4g+3.
__global__ __launch_bounds__(256) void edge_mlp(
    const float* __restrict__ PQ,         // [N,128]
    const int* __restrict__ edge_index,   // [2,E] (int32 from harness)
    const float* __restrict__ b1,         // [64]
    const float* __restrict__ W2,         // [64]
    const float* __restrict__ b2,         // [1]
    float* __restrict__ out,              // [E]
    int E)
{
    const int t = threadIdx.x;
    const int g = t & 15;
    const int e = blockIdx.x * 16 + (t >> 4);
    if (e >= E) return;

    const int src = edge_index[e];
    const int dst = edge_index[E + e];

    float4 p = *(const float4*)&PQ[(size_t)src * 128 + g * 4];
    float4 q = *(const float4*)&PQ[(size_t)dst * 128 + 64 + g * 4];
    float4 bb = ((const float4*)b1)[g];
    float4 w  = ((const float4*)W2)[g];

    float hx = fmaxf(p.x + q.x + bb.x, 0.f);
    float hy = fmaxf(p.y + q.y + bb.y, 0.f);
    float hz = fmaxf(p.z + q.z + bb.z, 0.f);
    float hw = fmaxf(p.w + q.w + bb.w, 0.f);
    float partial = hx * w.x + hy * w.y + hz * w.z + hw * w.w;

    // reduce across the 16-lane group (xor butterfly stays inside the group)
    #pragma unroll
    for (int off = 8; off >= 1; off >>= 1)
        partial += __shfl_xor(partial, off, 64);

    if (g == 0) out[e] = partial + b2[0];
}

extern "C" void kernel_launch(void* const* d_in, const int* in_sizes, int n_in,
                              void* d_out, int out_size, void* d_ws, size_t ws_size,
                              hipStream_t stream) {
    const float* node_emb  = (const float*)d_in[0];
    const int*   edge_index = (const int*)d_in[1];
    const float* W1 = (const float*)d_in[2];
    const float* b1 = (const float*)d_in[3];
    const float* W2 = (const float*)d_in[4];
    const float* b2 = (const float*)d_in[5];
    float* out = (float*)d_out;

    const int n_nodes = in_sizes[0] / HIDDEN;     // 50000
    const int E = in_sizes[1] / 2;                // 800000

    float* PQ = (float*)d_ws;                     // [n_nodes][128] fp32 = 25.6 MB

    const int grid1 = (n_nodes + 31) / 32;
    precompute_pq<<<grid1, 256, 0, stream>>>(node_emb, W1, PQ, n_nodes);

    const int grid2 = (E + 15) / 16;              // 16 edges per block
    edge_mlp<<<grid2, 256, 0, stream>>>(PQ, edge_index, b1, W2, b2, out, E);
}

// Round 2
// 120.244 us; speedup vs baseline: 1.8851x; 1.8851x over previous
//
#include <hip/hip_runtime.h>

// ViewLearner edge-scorer, factored:
//   PQ[n] = [ node_emb[n] @ W1_top | node_emb[n] @ W1_bot ]  (128 outs/node)
//   logit[e] = relu(PQ[src].P + PQ[dst].Q + b1) . W2 + b2
// Kernel 1: bf16 MFMA GEMM  [50000x128] @ [128x128] -> PQ stored fp16 in d_ws.
// Kernel 2: 8 lanes/edge gather fp16 PQ (two contiguous 128B segments), tiny MLP.

#define HIDDEN 128

typedef __attribute__((ext_vector_type(8))) short bf16x8;
typedef __attribute__((ext_vector_type(4))) float f32x4;
typedef __attribute__((ext_vector_type(8))) _Float16 half8;

__device__ inline unsigned short f32_to_bf16(float f) {
    unsigned int u = __float_as_uint(f);
    unsigned int r = (u + 0x7fffu + ((u >> 16) & 1u)) >> 16;
    return (unsigned short)r;
}

// ---------------- Kernel 1: PQ precompute via bf16 MFMA ---------------------
// Block: 256 threads (4 waves), tile 128 rows x 128 cols, K=128.
// LDS: As[128][136] bf16 (pad +8 keeps 16B align, breaks bank stride) +
//      Bt[128][136] bf16 (B transposed: Bt[j][k] = B[k][j]).  68 KB total.
__global__ __launch_bounds__(256) void precompute_pq_mfma(
    const float* __restrict__ node_emb,   // [N,128]
    const float* __restrict__ W1,         // [256,64] row-major
    _Float16* __restrict__ PQ,            // [N,128] fp16
    int n_nodes)
{
    __shared__ unsigned short As[128 * 136];
    __shared__ unsigned short Bt[128 * 136];

    const int t = threadIdx.x;
    const int m0 = blockIdx.x * 128;

    // Stage A tile: 128x128 fp32 -> bf16, vectorized float4 -> ushort4.
    #pragma unroll 4
    for (int s = 0; s < 16; ++s) {
        int slot = s * 256 + t;              // 0..4095 float4 slots
        int row = slot >> 5;                 // 32 float4 per row
        int k0 = (slot & 31) * 4;
        int m = m0 + row;
        float4 v = make_float4(0.f, 0.f, 0.f, 0.f);
        if (m < n_nodes) v = *(const float4*)&node_emb[(size_t)m * 128 + k0];
        ushort4 w;
        w.x = f32_to_bf16(v.x); w.y = f32_to_bf16(v.y);
        w.z = f32_to_bf16(v.z); w.w = f32_to_bf16(v.w);
        *(ushort4*)&As[row * 136 + k0] = w;
    }
    // Stage Bt: coalesced W1 read, strided LDS write (once per block, cheap).
    // B[k][j] = (j<64) ? W1[k][j] : W1[k+128][j-64];  Bt[j][k] = B[k][j].
    for (int u = t; u < 256 * 64; u += 256) {
        int r = u >> 6;                      // W1 row 0..255
        int c = u & 63;                      // W1 col 0..63
        int j = (r < 128) ? c : (c + 64);
        int k = r & 127;
        Bt[j * 136 + k] = f32_to_bf16(W1[u]);
    }
    __syncthreads();

    const int wave = t >> 6;
    const int lane = t & 63;
    const int lrow = lane & 15;
    const int kq = (lane >> 4) * 8;          // k sub-offset within K32 step

    f32x4 acc[2][8];
    #pragma unroll
    for (int rs = 0; rs < 2; ++rs)
        #pragma unroll
        for (int c = 0; c < 8; ++c)
            acc[rs][c] = (f32x4){0.f, 0.f, 0.f, 0.f};

    #pragma unroll
    for (int k0 = 0; k0 < 128; k0 += 32) {
        bf16x8 a[2];
        #pragma unroll
        for (int rs = 0; rs < 2; ++rs)
            a[rs] = *(const bf16x8*)&As[(wave * 32 + rs * 16 + lrow) * 136 + k0 + kq];
        #pragma unroll
        for (int c = 0; c < 8; ++c) {
            bf16x8 b = *(const bf16x8*)&Bt[(c * 16 + lrow) * 136 + k0 + kq];
            acc[0][c] = __builtin_amdgcn_mfma_f32_16x16x32_bf16(a[0], b, acc[0][c], 0, 0, 0);
            acc[1][c] = __builtin_amdgcn_mfma_f32_16x16x32_bf16(a[1], b, acc[1][c], 0, 0, 0);
        }
    }

    // Epilogue: C/D layout col=lane&15, row=(lane>>4)*4+reg.
    const int rbase = (lane >> 4) * 4;
    #pragma unroll
    for (int rs = 0; rs < 2; ++rs) {
        #pragma unroll
        for (int reg = 0; reg < 4; ++reg) {
            int m = m0 + wave * 32 + rs * 16 + rbase + reg;
            if (m < n_nodes) {
                #pragma unroll
                for (int c = 0; c < 8; ++c) {
                    int col = c * 16 + lrow;
                    PQ[(size_t)m * 128 + col] = (_Float16)acc[rs][c][reg];
                }
            }
        }
    }
}

// ---------------- Kernel 2: per-edge gather + tiny MLP (fp16 PQ) ------------
// 8 lanes per edge; lane g handles channels 8g..8g+7 (16B half8 loads).
__global__ __launch_bounds__(256) void edge_mlp16(
    const _Float16* __restrict__ PQ,      // [N,128] fp16
    const int* __restrict__ edge_index,   // [2,E] int32
    const float* __restrict__ b1,         // [64]
    const float* __restrict__ W2,         // [64]
    const float* __restrict__ b2,         // [1]
    float* __restrict__ out,              // [E]
    int E)
{
    const int t = threadIdx.x;
    const int g = t & 7;
    const int e = blockIdx.x * 32 + (t >> 3);
    if (e >= E) return;

    const int src = edge_index[e];
    const int dst = edge_index[E + e];

    half8 p = *(const half8*)&PQ[(size_t)src * 128 + g * 8];
    half8 q = *(const half8*)&PQ[(size_t)dst * 128 + 64 + g * 8];
    float4 bA = *(const float4*)&b1[g * 8];
    float4 bB = *(const float4*)&b1[g * 8 + 4];
    float4 wA = *(const float4*)&W2[g * 8];
    float4 wB = *(const float4*)&W2[g * 8 + 4];

    float partial = 0.f;
    partial += fmaxf((float)p[0] + (float)q[0] + bA.x, 0.f) * wA.x;
    partial += fmaxf((float)p[1] + (float)q[1] + bA.y, 0.f) * wA.y;
    partial += fmaxf((float)p[2] + (float)q[2] + bA.z, 0.f) * wA.z;
    partial += fmaxf((float)p[3] + (float)q[3] + bA.w, 0.f) * wA.w;
    partial += fmaxf((float)p[4] + (float)q[4] + bB.x, 0.f) * wB.x;
    partial += fmaxf((float)p[5] + (float)q[5] + bB.y, 0.f) * wB.y;
    partial += fmaxf((float)p[6] + (float)q[6] + bB.z, 0.f) * wB.z;
    partial += fmaxf((float)p[7] + (float)q[7] + bB.w, 0.f) * wB.w;

    partial += __shfl_xor(partial, 1, 64);
    partial += __shfl_xor(partial, 2, 64);
    partial += __shfl_xor(partial, 4, 64);

    if (g == 0) out[e] = partial + b2[0];
}

extern "C" void kernel_launch(void* const* d_in, const int* in_sizes, int n_in,
                              void* d_out, int out_size, void* d_ws, size_t ws_size,
                              hipStream_t stream) {
    const float* node_emb   = (const float*)d_in[0];
    const int*   edge_index = (const int*)d_in[1];
    const float* W1 = (const float*)d_in[2];
    const float* b1 = (const float*)d_in[3];
    const float* W2 = (const float*)d_in[4];
    const float* b2 = (const float*)d_in[5];
    float* out = (float*)d_out;

    const int n_nodes = in_sizes[0] / HIDDEN;     // 50000
    const int E = in_sizes[1] / 2;                // 800000

    _Float16* PQ = (_Float16*)d_ws;               // [n_nodes][128] fp16 = 12.8 MB

    const int grid1 = (n_nodes + 127) / 128;
    precompute_pq_mfma<<<grid1, 256, 0, stream>>>(node_emb, W1, PQ, n_nodes);

    const int grid2 = (E + 31) / 32;              // 32 edges per block
    edge_mlp16<<<grid2, 256, 0, stream>>>(PQ, edge_index, b1, W2, b2, out, E);
}

// Round 3
// 115.160 us; speedup vs baseline: 1.9683x; 1.0441x over previous
//
#include <hip/hip_runtime.h>
#include <hip/hip_bf16.h>

// ViewLearner edge-scorer, factored:
//   PQ[n] = [ node_emb[n] @ W1_top + b1 | node_emb[n] @ W1_bot ]   (fp16, [N][128])
//   logit[e] = relu(P'[src] + Q[dst]) . W2 + b2
// Kernel 1: bf16 MFMA GEMM, A streamed global->reg in fragment layout (no A LDS),
//           B^T staged once in LDS, epilogue transposed through LDS -> half8 stores.
// Kernel 2: 8 lanes/edge, 2 edges/thread, fp16 PQ gather (128B line per gather).

#define HIDDEN 128

typedef __attribute__((ext_vector_type(8))) short bf16x8;
typedef __attribute__((ext_vector_type(4))) float f32x4;
typedef __attribute__((ext_vector_type(8))) _Float16 half8;

__device__ inline unsigned short f32_to_bf16(float f) {
    unsigned int u = __float_as_uint(f);
    unsigned int r = (u + 0x7fffu + ((u >> 16) & 1u)) >> 16;
    return (unsigned short)r;
}

// ---------------- Kernel 1: PQ precompute via bf16 MFMA ---------------------
// 256 threads = 4 waves; block tile 64 rows x 128 cols, K=128.
// Wave w computes rows w*16..w*16+15 (one 16x16x32 MFMA row-tile, 8 col-tiles).
__global__ __launch_bounds__(256, 2) void precompute_pq_mfma(
    const float* __restrict__ node_emb,   // [N,128]
    const float* __restrict__ W1,         // [256,64] row-major
    const float* __restrict__ b1,         // [64]
    _Float16* __restrict__ PQ,            // [N,128] fp16 (P has b1 folded in)
    int n_nodes)
{
    __shared__ unsigned short Bt[128 * 136];  // B^T in bf16, pad stride 136 (34.8 KB)
    __shared__ _Float16 Out[64 * 136];        // epilogue transpose buffer (17.4 KB)

    const int t = threadIdx.x;
    const int wave = t >> 6, lane = t & 63;
    const int lrow = lane & 15;
    const int kq = (lane >> 4) * 8;           // k sub-offset within a K32 step
    const int m0 = blockIdx.x * 64;
    const int m = m0 + wave * 16 + lrow;
    const bool valid = (m < n_nodes);

    // ---- A: direct global->register in MFMA A-fragment layout.
    // Lane needs A[m][k0+kq .. +7] for k0 in {0,32,64,96}: 8 independent float4s.
    // The 4 lanes sharing m (kq=0,8,16,24 within each K32) jointly cover each
    // 128B cacheline chunk -> full line utilization.
    const float* arow = node_emb + (size_t)(valid ? m : 0) * HIDDEN + kq;
    float4 aLo[4], aHi[4];
    #pragma unroll
    for (int i = 0; i < 4; ++i) {
        if (valid) {
            aLo[i] = *(const float4*)(arow + i * 32);
            aHi[i] = *(const float4*)(arow + i * 32 + 4);
        } else {
            aLo[i] = make_float4(0.f, 0.f, 0.f, 0.f);
            aHi[i] = aLo[i];
        }
    }

    // ---- B: stage Bt[j][k] = B[k][j], B[k][j] = (j<64)?W1[k][j]:W1[k+128][j-64].
    // Coalesced float4 reads of W1; scattered b16 LDS writes (one-time, small).
    #pragma unroll
    for (int it = 0; it < 16; ++it) {
        int slot = it * 256 + t;              // float4 slot 0..4095
        int r = slot >> 4;                    // W1 row 0..255
        int c4 = (slot & 15) * 4;             // W1 col 0,4,..,60
        float4 v = *(const float4*)&W1[r * 64 + c4];
        int j = (r < 128) ? c4 : (c4 + 64);
        int k = r & 127;
        Bt[(j + 0) * 136 + k] = f32_to_bf16(v.x);
        Bt[(j + 1) * 136 + k] = f32_to_bf16(v.y);
        Bt[(j + 2) * 136 + k] = f32_to_bf16(v.z);
        Bt[(j + 3) * 136 + k] = f32_to_bf16(v.w);
    }
    __syncthreads();

    // ---- MFMA main: 4 K-steps x 8 col-tiles.
    f32x4 acc[8];
    #pragma unroll
    for (int c = 0; c < 8; ++c) acc[c] = (f32x4){0.f, 0.f, 0.f, 0.f};

    #pragma unroll
    for (int k0i = 0; k0i < 4; ++k0i) {
        union { bf16x8 v; __hip_bfloat162 h[4]; } ua;
        ua.h[0] = __float22bfloat162_rn(make_float2(aLo[k0i].x, aLo[k0i].y));
        ua.h[1] = __float22bfloat162_rn(make_float2(aLo[k0i].z, aLo[k0i].w));
        ua.h[2] = __float22bfloat162_rn(make_float2(aHi[k0i].x, aHi[k0i].y));
        ua.h[3] = __float22bfloat162_rn(make_float2(aHi[k0i].z, aHi[k0i].w));
        const int kbase = k0i * 32 + kq;
        #pragma unroll
        for (int c = 0; c < 8; ++c) {
            bf16x8 bf = *(const bf16x8*)&Bt[(c * 16 + lrow) * 136 + kbase];
            acc[c] = __builtin_amdgcn_mfma_f32_16x16x32_bf16(ua.v, bf, acc[c], 0, 0, 0);
        }
    }

    // ---- Epilogue: C/D layout col=lane&15, row=(lane>>4)*4+reg.
    // Transpose through LDS, fold b1 into P cols, then coalesced half8 stores.
    const int rbase = (lane >> 4) * 4;
    #pragma unroll
    for (int c = 0; c < 8; ++c) {
        int col = c * 16 + lrow;
        float bias = (col < 64) ? b1[col] : 0.f;
        #pragma unroll
        for (int reg = 0; reg < 4; ++reg) {
            int row = wave * 16 + rbase + reg;
            Out[row * 136 + col] = (_Float16)(acc[c][reg] + bias);
        }
    }
    __syncthreads();
    #pragma unroll
    for (int i = 0; i < 4; ++i) {
        int idx = i * 256 + t;                // 1024 half8 slots
        int row = idx >> 4;
        int cg = (idx & 15) * 8;
        int mm = m0 + row;
        if (mm < n_nodes) {
            half8 v = *(const half8*)&Out[row * 136 + cg];
            *(half8*)&PQ[(size_t)mm * HIDDEN + cg] = v;
        }
    }
}

// ---------------- Kernel 2: per-edge gather + tiny MLP (fp16 PQ) ------------
// 8 lanes per edge, 2 edges per thread (4 independent gather chains in flight).
__global__ __launch_bounds__(256, 4) void edge_mlp16(
    const _Float16* __restrict__ PQ,      // [N,128] fp16
    const int* __restrict__ edge_index,   // [2,E] int32
    const float* __restrict__ W2,         // [64]
    const float* __restrict__ b2,         // [1]
    float* __restrict__ out,              // [E]
    int E)
{
    const int t = threadIdx.x;
    const int g = t & 7;
    const int slot = t >> 3;              // 0..31
    const int e0 = blockIdx.x * 64 + slot;
    const int e1 = e0 + 32;

    float4 wA = *(const float4*)&W2[g * 8];
    float4 wB = *(const float4*)&W2[g * 8 + 4];

    const bool v0 = e0 < E, v1 = e1 < E;
    int src0 = 0, dst0 = 0, src1 = 0, dst1 = 0;
    if (v0) { src0 = edge_index[e0]; dst0 = edge_index[E + e0]; }
    if (v1) { src1 = edge_index[e1]; dst1 = edge_index[E + e1]; }

    half8 p0{}, q0{}, p1{}, q1{};
    if (v0) {
        p0 = *(const half8*)&PQ[(size_t)src0 * HIDDEN + g * 8];
        q0 = *(const half8*)&PQ[(size_t)dst0 * HIDDEN + 64 + g * 8];
    }
    if (v1) {
        p1 = *(const half8*)&PQ[(size_t)src1 * HIDDEN + g * 8];
        q1 = *(const half8*)&PQ[(size_t)dst1 * HIDDEN + 64 + g * 8];
    }

    float s0 = 0.f, s1 = 0.f;
    s0 += fmaxf((float)p0[0] + (float)q0[0], 0.f) * wA.x;
    s0 += fmaxf((float)p0[1] + (float)q0[1], 0.f) * wA.y;
    s0 += fmaxf((float)p0[2] + (float)q0[2], 0.f) * wA.z;
    s0 += fmaxf((float)p0[3] + (float)q0[3], 0.f) * wA.w;
    s0 += fmaxf((float)p0[4] + (float)q0[4], 0.f) * wB.x;
    s0 += fmaxf((float)p0[5] + (float)q0[5], 0.f) * wB.y;
    s0 += fmaxf((float)p0[6] + (float)q0[6], 0.f) * wB.z;
    s0 += fmaxf((float)p0[7] + (float)q0[7], 0.f) * wB.w;

    s1 += fmaxf((float)p1[0] + (float)q1[0], 0.f) * wA.x;
    s1 += fmaxf((float)p1[1] + (float)q1[1], 0.f) * wA.y;
    s1 += fmaxf((float)p1[2] + (float)q1[2], 0.f) * wA.z;
    s1 += fmaxf((float)p1[3] + (float)q1[3], 0.f) * wA.w;
    s1 += fmaxf((float)p1[4] + (float)q1[4], 0.f) * wB.x;
    s1 += fmaxf((float)p1[5] + (float)q1[5], 0.f) * wB.y;
    s1 += fmaxf((float)p1[6] + (float)q1[6], 0.f) * wB.z;
    s1 += fmaxf((float)p1[7] + (float)q1[7], 0.f) * wB.w;

    // xor-butterfly inside each 8-lane group (independent trees interleave)
    s0 += __shfl_xor(s0, 1, 64);  s1 += __shfl_xor(s1, 1, 64);
    s0 += __shfl_xor(s0, 2, 64);  s1 += __shfl_xor(s1, 2, 64);
    s0 += __shfl_xor(s0, 4, 64);  s1 += __shfl_xor(s1, 4, 64);

    if (g == 0) {
        float bb = b2[0];
        if (v0) out[e0] = s0 + bb;
        if (v1) out[e1] = s1 + bb;
    }
}

extern "C" void kernel_launch(void* const* d_in, const int* in_sizes, int n_in,
                              void* d_out, int out_size, void* d_ws, size_t ws_size,
                              hipStream_t stream) {
    const float* node_emb   = (const float*)d_in[0];
    const int*   edge_index = (const int*)d_in[1];
    const float* W1 = (const float*)d_in[2];
    const float* b1 = (const float*)d_in[3];
    const float* W2 = (const float*)d_in[4];
    const float* b2 = (const float*)d_in[5];
    float* out = (float*)d_out;

    const int n_nodes = in_sizes[0] / HIDDEN;     // 50000
    const int E = in_sizes[1] / 2;                // 800000

    _Float16* PQ = (_Float16*)d_ws;               // [n_nodes][128] fp16 = 12.8 MB

    const int grid1 = (n_nodes + 63) / 64;        // 782
    precompute_pq_mfma<<<grid1, 256, 0, stream>>>(node_emb, W1, b1, PQ, n_nodes);

    const int grid2 = (E + 63) / 64;              // 12500
    edge_mlp16<<<grid2, 256, 0, stream>>>(PQ, edge_index, W2, b2, out, E);
}